// Round 5
// baseline (193.114 us; speedup 1.0000x reference)
//
#include <hip/hip_runtime.h>
#include <hip/hip_fp16.h>
#include <math.h>

#define EPS 0.05f
#define INV_EPS 20.0f
#define BIGF 1e30f

typedef short bf16x8 __attribute__((ext_vector_type(8)));
typedef float f32x4 __attribute__((ext_vector_type(4)));

__device__ __forceinline__ unsigned f2bf(float x) {
  unsigned u = __float_as_uint(x);
  return (u + 0x7fffu + ((u >> 16) & 1u)) >> 16;  // RNE f32->bf16
}
__device__ __forceinline__ unsigned pk2(float a, float b) {
  return (f2bf(a) & 0xffffu) | (f2bf(b) << 16);
}

// per-batch K-data layout in ws (floats): Kr[48*116] | KT[112*52] | vec[192]
#define KRS 5568
#define KTS 5824
#define VECOFF (KRS + KTS)       // 11392
#define KSTRIDE 11584
// vec: [0,48)=rv, [48,160)=cv, 160=inv_n0, 161=inv_n1, 162=n0, 163=n1

// ---- k_gram LDS arena (bytes) ----
#define S_HSA  0        // short[128][72] = 18432
#define S_HSB  18432    //              -> 36864
#define S_GM   0        // half[128][130] = 33280 (alias, Hs dead)
#define S_KT   0        // float[112][52] = 23296 (alias, Gm dead)
#define S_KR   36864    // float[48][116] = 22272 -> 59136
#define S_DIAG 59136    // f32[128] -> 59648
#define S_IA   59648    // int[48]  -> 59840
#define S_IB   59840    // int[112] -> 60288
#define S_RV   60288    // f32[48]  -> 60480
#define S_CV   60480    // f32[112] -> 60928
#define S_CNT  60928    // int[4]   -> 60944
#define SMEM_SZ 60960

__global__ __launch_bounds__(512)
void k_gram(const float* __restrict__ H, const int* __restrict__ ttid,
            const int* __restrict__ amask, float* __restrict__ kdat)
{
  __shared__ __align__(16) char smem[SMEM_SZ];
  const int t = threadIdx.x;
  const int b = blockIdx.x;

  short*  HsA  = (short*)(smem + S_HSA);
  short*  HsB  = (short*)(smem + S_HSB);
  __half* Gm   = (__half*)(smem + S_GM);
  float*  KT   = (float*)(smem + S_KT);
  float*  Kr   = (float*)(smem + S_KR);
  float*  diag = (float*)(smem + S_DIAG);
  int*    ia   = (int*)(smem + S_IA);
  int*    ib   = (int*)(smem + S_IB);
  float*  rv   = (float*)(smem + S_RV);
  float*  cv   = (float*)(smem + S_CV);
  int*    cnts = (int*)(smem + S_CNT);

  const int lane = t & 63;
  const int w = t >> 6;

  // ---- Phase A: compact index lists ----
  int flagA = 0, flagB = 0;
  unsigned long long mA = 0, mB = 0;
  if (t < 128) {
    int a_ = amask[b*128 + t], tt_ = ttid[b*128 + t];
    flagA = (a_ == 1 && tt_ == 0);
    flagB = (a_ == 1 && tt_ == 1);
    mA = __ballot(flagA);
    mB = __ballot(flagB);
    if (lane == 0) { cnts[w] = __popcll(mA); cnts[2 + w] = __popcll(mB); }
  }
  __syncthreads();
  const int n0 = cnts[0] + cnts[1];
  const int n1 = cnts[2] + cnts[3];
  if (t < 128) {
    int offA = (w == 1) ? cnts[0] : 0;
    int offB = (w == 1) ? cnts[2] : 0;
    unsigned long long below = (1ull << lane) - 1ull;
    if (flagA) ia[offA + __popcll(mA & below)] = t;
    if (flagB) ib[offB + __popcll(mB & below)] = t;
  }

  // ---- Phase B: Gram via bf16 MFMA, depth-2 prefetched staging ----
  const int wv = t >> 6;
  const int fm = lane & 15, fg = lane >> 4;
  f32x4 acc[8];
  #pragma unroll
  for (int ct = 0; ct < 8; ct++) {
    acc[ct][0] = 0.f; acc[ct][1] = 0.f; acc[ct][2] = 0.f; acc[ct][3] = 0.f;
  }
  const float* Hb = H + (size_t)b * (128 * 768);
  const int srow = t >> 2, sc0 = (t & 3) * 16;
  const float* srcB = Hb + srow * 768 + sc0;
  float4 a0 = *(const float4*)(srcB);
  float4 a1 = *(const float4*)(srcB + 4);
  float4 a2 = *(const float4*)(srcB + 8);
  float4 a3 = *(const float4*)(srcB + 12);
  {   // store tile 0 -> HsA
    uint4 w0, w1;
    w0.x = pk2(a0.x, a0.y); w0.y = pk2(a0.z, a0.w);
    w0.z = pk2(a1.x, a1.y); w0.w = pk2(a1.z, a1.w);
    w1.x = pk2(a2.x, a2.y); w1.y = pk2(a2.z, a2.w);
    w1.z = pk2(a3.x, a3.y); w1.w = pk2(a3.z, a3.w);
    *(uint4*)(HsA + srow * 72 + sc0) = w0;
    *(uint4*)(HsA + srow * 72 + sc0 + 8) = w1;
  }
  // prefetch tiles 1 (pa) and 2 (pb)
  a0 = *(const float4*)(srcB + 64);
  a1 = *(const float4*)(srcB + 68);
  a2 = *(const float4*)(srcB + 72);
  a3 = *(const float4*)(srcB + 76);
  float4 b0 = *(const float4*)(srcB + 128);
  float4 b1 = *(const float4*)(srcB + 132);
  float4 b2 = *(const float4*)(srcB + 136);
  float4 b3 = *(const float4*)(srcB + 140);
  for (int kc = 0; kc < 12; kc++) {
    __syncthreads();     // tile kc visible in cur
    short* cur = (kc & 1) ? HsB : HsA;
    short* nxt = (kc & 1) ? HsA : HsB;
    if (kc < 11) {       // store tile kc+1 (held in pa)
      uint4 w0, w1;
      w0.x = pk2(a0.x, a0.y); w0.y = pk2(a0.z, a0.w);
      w0.z = pk2(a1.x, a1.y); w0.w = pk2(a1.z, a1.w);
      w1.x = pk2(a2.x, a2.y); w1.y = pk2(a2.z, a2.w);
      w1.z = pk2(a3.x, a3.y); w1.w = pk2(a3.z, a3.w);
      *(uint4*)(nxt + srow * 72 + sc0) = w0;
      *(uint4*)(nxt + srow * 72 + sc0 + 8) = w1;
    }
    if (kc < 10) {       // shift pb->pa, prefetch tile kc+3
      a0 = b0; a1 = b1; a2 = b2; a3 = b3;
      if (kc < 9) {
        const float* s2 = srcB + (kc + 3) * 64;
        b0 = *(const float4*)(s2);
        b1 = *(const float4*)(s2 + 4);
        b2 = *(const float4*)(s2 + 8);
        b3 = *(const float4*)(s2 + 12);
      }
    }
    #pragma unroll
    for (int ks = 0; ks < 2; ks++) {
      bf16x8 afrag = *(const bf16x8*)(cur + (wv * 16 + fm) * 72 + ks * 32 + fg * 8);
      #pragma unroll
      for (int ct = 0; ct < 8; ct++) {
        bf16x8 bfrag = *(const bf16x8*)(cur + (ct * 16 + fm) * 72 + ks * 32 + fg * 8);
        acc[ct] = __builtin_amdgcn_mfma_f32_16x16x32_bf16(afrag, bfrag, acc[ct], 0, 0, 0);
      }
    }
  }
  __syncthreads();       // all MFMA reads done; Hs dead -> Gm
  #pragma unroll
  for (int ct = 0; ct < 8; ct++) {
    int gc = ct * 16 + fm;
    #pragma unroll
    for (int q2 = 0; q2 < 4; q2++) {
      int gr = wv * 16 + fg * 4 + q2;
      Gm[gr * 130 + gc] = __float2half(acc[ct][q2]);
    }
  }
  if ((fm >> 2) == fg) diag[wv * 16 + fm] = acc[wv][fm & 3];  // f32 diag
  for (int e = t; e < 48 * 116; e += 512) Kr[e] = BIGF;
  __syncthreads();

  // ---- Phase C: compact Ce, shifts, K transform, KT ----
  for (int i = t >> 7; i < n0; i += 4) {
    int ra = ia[i];
    float di = diag[ra];
    for (int j = t & 127; j < n1; j += 128) {
      int cb = ib[j];
      float g = __half2float(Gm[ra * 130 + cb]);
      float d2 = fmaxf(di + diag[cb] - 2.0f * g, 1e-6f);
      Kr[i * 116 + j] = sqrtf(d2) * INV_EPS;
    }
  }
  __syncthreads();
  if (t < 192) {  // r_i = min_j Ce
    int r = t >> 2, c = t & 3;
    const float* row = Kr + r * 116 + c * 28;
    float mn = BIGF;
    #pragma unroll
    for (int g = 0; g < 7; g++) {
      float4 x = *(const float4*)(row + g * 4);
      mn = fminf(mn, fminf(fminf(x.x, x.y), fminf(x.z, x.w)));
    }
    mn = fminf(mn, __shfl_xor(mn, 1));
    mn = fminf(mn, __shfl_xor(mn, 2));
    if (c == 0) rv[r] = mn;
  }
  __syncthreads();
  if (t < 448) {  // c_j = min_{i<n0} (Ce - r_i)
    int cl = t >> 2, rr = t & 3;
    float mn = BIGF;
    #pragma unroll
    for (int g = 0; g < 12; g++) {
      int i = rr * 12 + g;
      float v = (i < n0) ? (Kr[i * 116 + cl] - rv[i]) : BIGF;
      mn = fminf(mn, v);
    }
    mn = fminf(mn, __shfl_xor(mn, 1));
    mn = fminf(mn, __shfl_xor(mn, 2));
    if (rr == 0) cv[cl] = mn;
  }
  __syncthreads();
  for (int i = t >> 7; i < 48; i += 4) {  // K = exp(min(r+c-Ce,0)) in place
    float ri = rv[i];
    for (int j = t & 127; j < 112; j += 128) {
      float ce = Kr[i * 116 + j];
      Kr[i * 116 + j] = __expf(fminf(ri + cv[j] - ce, 0.f));
    }
  }
  __syncthreads();       // Gm dead -> KT
  for (int i = t >> 7; i < 48; i += 4) {
    int j = t & 127;
    if (j < 112) KT[j * 52 + i] = Kr[i * 116 + j];
  }
  __syncthreads();

  // ---- store compact problem to global ws ----
  float* Kg = kdat + (size_t)b * KSTRIDE;
  for (int e = t; e < KRS; e += 512) Kg[e] = Kr[e];
  for (int e = t; e < KTS; e += 512) Kg[KRS + e] = KT[e];
  float* vec = Kg + VECOFF;
  if (t < 48) vec[t] = rv[t];
  if (t >= 64 && t < 176) vec[48 + (t - 64)] = cv[t - 64];
  if (t == 0) {
    vec[160] = 1.0f / (float)n0;
    vec[161] = 1.0f / (float)n1;
    vec[162] = (float)n0;
    vec[163] = (float)n1;
  }
}

__global__ __launch_bounds__(64, 1)
void k_sink(const float* __restrict__ kdat, float* __restrict__ dcross)
{
  const int b = blockIdx.x, l = threadIdx.x;
  __shared__ __align__(16) float uv[48];
  __shared__ __align__(16) float vv[112];

  const float* Kg  = kdat + (size_t)b * KSTRIDE;
  const float* KTg = Kg + KRS;
  const float* vec = Kg + VECOFF;

  const float rl  = vec[(l < 48) ? l : 47];
  const float cv1 = vec[48 + l];
  const float cv2 = (l < 48) ? vec[48 + 64 + l] : 0.f;
  const float inv_n0 = vec[160], inv_n1 = vec[161];
  const int n0 = (int)vec[162], n1 = (int)vec[163];

  const int r48 = (l < 48) ? l : 47;
  const int j2ok = (l < 48);
  const int c2 = j2ok ? (l + 64) : l;
  const float a_l = (l < n0) ? inv_n0 : 0.f;
  const float b1w = (l < n1) ? inv_n1 : 0.f;
  const float b2w = (j2ok && c2 < n1) ? inv_n1 : 0.f;

  // K row + two KT rows into registers
  float4 KR[28], KA[12], KB[12];
  #pragma unroll
  for (int g = 0; g < 28; g++) KR[g] = *(const float4*)(Kg + r48 * 116 + 4 * g);
  #pragma unroll
  for (int g = 0; g < 12; g++) {
    KA[g] = *(const float4*)(KTg + l * 52 + 4 * g);
    KB[g] = *(const float4*)(KTg + c2 * 52 + 4 * g);
  }

  // init v
  vv[l] = (l < n1) ? inv_n1 * __expf(-cv1) : 0.f;
  if (j2ok) vv[l + 64] = (l + 64 < n1) ? inv_n1 * __expf(-cv2) : 0.f;
  __asm__ volatile("s_waitcnt lgkmcnt(0)" ::: "memory");

  float Sl = 1.f, Tc1 = 1.f, Tc2 = 1.f;
  for (int it = 0; it < 30; it++) {
    // u-step: lane l = row l
    float s0 = 0.f, s1 = 0.f, s2 = 0.f, s3 = 0.f;
    #pragma unroll
    for (int g = 0; g < 28; g++) {
      float4 v4 = *(const float4*)(vv + 4 * g);   // LDS broadcast
      s0 += KR[g].x * v4.x; s1 += KR[g].y * v4.y;
      s2 += KR[g].z * v4.z; s3 += KR[g].w * v4.w;
    }
    float S = (s0 + s1) + (s2 + s3);
    Sl = S;
    if (l < 48) uv[l] = a_l * __builtin_amdgcn_rcpf(S);
    __asm__ volatile("s_waitcnt lgkmcnt(0)" ::: "memory");
    // v-step: lane l = cols l, l+64
    float p0 = 0.f, p1 = 0.f, q0 = 0.f, q1 = 0.f;
    #pragma unroll
    for (int g = 0; g < 12; g++) {
      float4 u4 = *(const float4*)(uv + 4 * g);   // LDS broadcast
      p0 += KA[g].x * u4.x + KA[g].z * u4.z;
      p1 += KA[g].y * u4.y + KA[g].w * u4.w;
      q0 += KB[g].x * u4.x + KB[g].z * u4.z;
      q1 += KB[g].y * u4.y + KB[g].w * u4.w;
    }
    float T1 = p0 + p1, T2 = q0 + q1;
    Tc1 = T1; Tc2 = T2;
    vv[l] = b1w * __builtin_amdgcn_rcpf(T1);
    if (j2ok) vv[l + 64] = b2w * __builtin_amdgcn_rcpf(T2);
    __asm__ volatile("s_waitcnt lgkmcnt(0)" ::: "memory");
  }
  // dual value, 64-lane butterfly
  float val = (l < n0) ? inv_n0 * (rl - __logf(Sl)) : 0.f;
  if (l < n1) val += inv_n1 * (cv1 - __logf(Tc1));
  if (j2ok && c2 < n1) val += inv_n1 * (cv2 - __logf(Tc2));
  #pragma unroll
  for (int d = 1; d < 64; d <<= 1) val += __shfl_xor(val, d);
  if (l == 0) dcross[b] = EPS * val;
}

__global__ __launch_bounds__(512)
void k_mlp(const float* __restrict__ H, const int* __restrict__ ttid,
           const int* __restrict__ amask,
           const float* __restrict__ Wc, const float* __restrict__ bc,
           const float* __restrict__ Ws, const float* __restrict__ bs,
           const float* __restrict__ gate,
           float* __restrict__ cnt, float* __restrict__ fused)
{
  const int b = blockIdx.x, t = threadIdx.x;
  __shared__ __align__(16) float repv[1536];
  __shared__ float afl[128], bfl[128], red[2];

  if (t < 128) {
    int a_ = amask[b*128 + t], tt_ = ttid[b*128 + t];
    afl[t] = (a_ == 1 && tt_ == 0) ? 1.0f : 0.0f;
    bfl[t] = (a_ == 1 && tt_ == 1) ? 1.0f : 0.0f;
  }
  __syncthreads();
  if (t < 64) {
    float s = afl[t] + afl[t + 64];
    #pragma unroll
    for (int d = 32; d > 0; d >>= 1) s += __shfl_down(s, d);
    if (t == 0) red[0] = s;
  } else if (t < 128) {
    int l = t - 64;
    float s = bfl[l] + bfl[l + 64];
    #pragma unroll
    for (int d = 32; d > 0; d >>= 1) s += __shfl_down(s, d);
    if (l == 0) red[1] = s;
  }
  __syncthreads();
  const float n0 = fmaxf(red[0], 1.0f), n1 = fmaxf(red[1], 1.0f);
  if (t == 0) { cnt[b*2] = n0; cnt[b*2 + 1] = n1; }

  const float* Hb = H + (size_t)b * (128 * 768);
  for (int d = t; d < 768; d += 512) {
    float s0 = 0.f, s1 = 0.f;
    #pragma unroll 4
    for (int i = 0; i < 128; i++) {
      float h = Hb[i * 768 + d];
      s0 += afl[i] * h;
      s1 += bfl[i] * h;
    }
    repv[768 + d] = s0 / n0 - s1 / n1;
    repv[d] = Hb[d];  // cls
  }
  __syncthreads();

  const int klane = t & 63, og = t >> 6;
  float4 rr[6];
  #pragma unroll
  for (int c4 = 0; c4 < 6; c4++)
    rr[c4] = *(const float4*)(repv + c4 * 256 + klane * 4);
  const float gg = 1.0f / (1.0f + __expf(-gate[0]));
  for (int oo = og; oo < 320; oo += 8) {
    const float* wrow = (oo < 256) ? (Wc + (size_t)oo * 1536)
                                   : (Ws + (size_t)(oo - 256) * 1536);
    float s = 0.f;
    #pragma unroll
    for (int c4 = 0; c4 < 6; c4++) {
      float4 w4 = *(const float4*)(wrow + c4 * 256 + klane * 4);
      s += rr[c4].x * w4.x + rr[c4].y * w4.y + rr[c4].z * w4.z + rr[c4].w * w4.w;
    }
    #pragma unroll
    for (int d = 32; d > 0; d >>= 1) s += __shfl_down(s, d);
    if (klane == 0) {
      float bias = (oo < 256) ? bc[oo] : bs[oo - 256];
      fused[b * 320 + oo] = (s + bias) * ((oo < 256) ? (1.0f - gg) : gg);
    }
  }
}

__global__ __launch_bounds__(128)
void k_final(const float* __restrict__ fused, const float* __restrict__ dcross,
             const float* __restrict__ cnt,
             const float* __restrict__ lnw, const float* __restrict__ lnb,
             const float* __restrict__ Wcls, const float* __restrict__ bcls,
             float* __restrict__ out)
{
  const int b = blockIdx.x, t = threadIdx.x;
  __shared__ float feat[321];
  __shared__ float sred[4];
  for (int i = t; i < 320; i += 128) feat[i] = fused[b * 320 + i];
  if (t == 0) {
    float n0 = cnt[b*2], n1 = cnt[b*2 + 1];
    float dsa = EPS * __logf(n0) + 0.001f;   // collapsed self-Sinkhorn
    float dsb = EPS * __logf(n1) + 0.001f;
    feat[320] = dcross[b] - 0.5f * (dsa + dsb);
  }
  __syncthreads();
  float s = 0.f;
  for (int i = t; i < 321; i += 128) s += feat[i];
  #pragma unroll
  for (int d = 32; d > 0; d >>= 1) s += __shfl_down(s, d);
  if ((t & 63) == 0) sred[t >> 6] = s;
  __syncthreads();
  const float mu = (sred[0] + sred[1]) * (1.0f / 321.0f);
  __syncthreads();
  float v = 0.f;
  for (int i = t; i < 321; i += 128) { float d2 = feat[i] - mu; v += d2 * d2; }
  #pragma unroll
  for (int d = 32; d > 0; d >>= 1) v += __shfl_down(v, d);
  if ((t & 63) == 0) sred[t >> 6] = v;
  __syncthreads();
  const float rstd = rsqrtf((sred[0] + sred[1]) * (1.0f / 321.0f) + 1e-5f);
  __syncthreads();
  float p0 = 0.f, p1 = 0.f;
  for (int i = t; i < 321; i += 128) {
    float h = (feat[i] - mu) * rstd * lnw[i] + lnb[i];
    p0 += h * Wcls[i];
    p1 += h * Wcls[321 + i];
  }
  #pragma unroll
  for (int d = 32; d > 0; d >>= 1) { p0 += __shfl_down(p0, d); p1 += __shfl_down(p1, d); }
  if ((t & 63) == 0) { sred[t >> 6] = p0; sred[2 + (t >> 6)] = p1; }
  __syncthreads();
  if (t == 0) {
    out[b * 2]     = sred[0] + sred[1] + bcls[0];
    out[b * 2 + 1] = sred[2] + sred[3] + bcls[1];
  }
}

extern "C" void kernel_launch(void* const* d_in, const int* in_sizes, int n_in,
                              void* d_out, int out_size, void* d_ws, size_t ws_size,
                              hipStream_t stream)
{
  (void)in_sizes; (void)n_in; (void)out_size; (void)ws_size;
  const float* H    = (const float*)d_in[0];
  const int*   tt   = (const int*)d_in[1];
  const int*   am   = (const int*)d_in[2];
  const float* Wc   = (const float*)d_in[3];
  const float* bc   = (const float*)d_in[4];
  const float* Ws   = (const float*)d_in[5];
  const float* bs   = (const float*)d_in[6];
  const float* gate = (const float*)d_in[7];
  const float* lnw  = (const float*)d_in[8];
  const float* lnb  = (const float*)d_in[9];
  const float* Wcls = (const float*)d_in[10];
  const float* bcls = (const float*)d_in[11];
  float* out = (float*)d_out;

  float* dcross = (float*)d_ws;        // 64
  float* cntv   = dcross + 64;         // 128
  float* fusedv = cntv + 128;          // 64*320
  float* kdat   = fusedv + 64 * 320;   // 64 * KSTRIDE floats (~2.97 MB)

  k_gram<<<dim3(64), dim3(512), 0, stream>>>(H, tt, am, kdat);
  k_sink<<<dim3(64), dim3(64), 0, stream>>>(kdat, dcross);
  k_mlp<<<dim3(64), dim3(512), 0, stream>>>(H, tt, am, Wc, bc, Ws, bs, gate,
                                            cntv, fusedv);
  k_final<<<dim3(64), dim3(128), 0, stream>>>(fusedv, dcross, cntv, lnw, lnb,
                                              Wcls, bcls, out);
}

// Round 6
// 158.959 us; speedup vs baseline: 1.2149x; 1.2149x over previous
//
#include <hip/hip_runtime.h>
#include <hip/hip_fp16.h>
#include <math.h>

#define EPS 0.05f
#define INV_EPS 20.0f
#define BIGF 1e30f

typedef short bf16x8 __attribute__((ext_vector_type(8)));
typedef float f32x4 __attribute__((ext_vector_type(4)));
typedef _Float16 f16x8 __attribute__((ext_vector_type(8)));
typedef _Float16 f16x4 __attribute__((ext_vector_type(4)));

__device__ __forceinline__ unsigned f2bf(float x) {
  unsigned u = __float_as_uint(x);
  return (u + 0x7fffu + ((u >> 16) & 1u)) >> 16;  // RNE f32->bf16
}
__device__ __forceinline__ unsigned pk2(float a, float b) {
  return (f2bf(a) & 0xffffu) | (f2bf(b) << 16);
}

// per-batch K-data layout in ws (floats): Kr[48*116] | KT[112*52] | vec[192]
#define KRS 5568
#define KTS 5824
#define VECOFF (KRS + KTS)       // 11392
#define KSTRIDE 11584
// vec: [0,48)=rv, [48,160)=cv, 160=inv_n0, 161=inv_n1, 162=n0, 163=n1

// ---- k_gram LDS arena (bytes) ----
#define S_HSA  0        // short[128][72] = 18432
#define S_HSB  18432    //              -> 36864
#define S_GM   0        // half[128][130] = 33280 (alias, Hs dead)
#define S_KT   0        // float[112][52] = 23296 (alias, Gm dead)
#define S_KR   36864    // float[48][116] = 22272 -> 59136
#define S_DIAG 59136    // f32[128] -> 59648
#define S_IA   59648    // int[48]  -> 59840
#define S_IB   59840    // int[112] -> 60288
#define S_RV   60288    // f32[48]  -> 60480
#define S_CV   60480    // f32[112] -> 60928
#define S_CNT  60928    // int[4]   -> 60944
#define SMEM_SZ 60960

__global__ __launch_bounds__(512)
void k_gram(const float* __restrict__ H, const int* __restrict__ ttid,
            const int* __restrict__ amask, float* __restrict__ kdat)
{
  __shared__ __align__(16) char smem[SMEM_SZ];
  const int t = threadIdx.x;
  const int b = blockIdx.x;

  short*  HsA  = (short*)(smem + S_HSA);
  short*  HsB  = (short*)(smem + S_HSB);
  __half* Gm   = (__half*)(smem + S_GM);
  float*  KT   = (float*)(smem + S_KT);
  float*  Kr   = (float*)(smem + S_KR);
  float*  diag = (float*)(smem + S_DIAG);
  int*    ia   = (int*)(smem + S_IA);
  int*    ib   = (int*)(smem + S_IB);
  float*  rv   = (float*)(smem + S_RV);
  float*  cv   = (float*)(smem + S_CV);
  int*    cnts = (int*)(smem + S_CNT);

  const int lane = t & 63;
  const int w = t >> 6;

  // ---- Phase A: compact index lists ----
  int flagA = 0, flagB = 0;
  unsigned long long mA = 0, mB = 0;
  if (t < 128) {
    int a_ = amask[b*128 + t], tt_ = ttid[b*128 + t];
    flagA = (a_ == 1 && tt_ == 0);
    flagB = (a_ == 1 && tt_ == 1);
    mA = __ballot(flagA);
    mB = __ballot(flagB);
    if (lane == 0) { cnts[w] = __popcll(mA); cnts[2 + w] = __popcll(mB); }
  }
  __syncthreads();
  const int n0 = cnts[0] + cnts[1];
  const int n1 = cnts[2] + cnts[3];
  if (t < 128) {
    int offA = (w == 1) ? cnts[0] : 0;
    int offB = (w == 1) ? cnts[2] : 0;
    unsigned long long below = (1ull << lane) - 1ull;
    if (flagA) ia[offA + __popcll(mA & below)] = t;
    if (flagB) ib[offB + __popcll(mB & below)] = t;
  }

  // ---- Phase B: Gram via bf16 MFMA, depth-2 prefetched staging ----
  const int wv = t >> 6;
  const int fm = lane & 15, fg = lane >> 4;
  f32x4 acc[8];
  #pragma unroll
  for (int ct = 0; ct < 8; ct++) {
    acc[ct][0] = 0.f; acc[ct][1] = 0.f; acc[ct][2] = 0.f; acc[ct][3] = 0.f;
  }
  const float* Hb = H + (size_t)b * (128 * 768);
  const int srow = t >> 2, sc0 = (t & 3) * 16;
  const float* srcB = Hb + srow * 768 + sc0;
  float4 a0 = *(const float4*)(srcB);
  float4 a1 = *(const float4*)(srcB + 4);
  float4 a2 = *(const float4*)(srcB + 8);
  float4 a3 = *(const float4*)(srcB + 12);
  {   // store tile 0 -> HsA
    uint4 w0, w1;
    w0.x = pk2(a0.x, a0.y); w0.y = pk2(a0.z, a0.w);
    w0.z = pk2(a1.x, a1.y); w0.w = pk2(a1.z, a1.w);
    w1.x = pk2(a2.x, a2.y); w1.y = pk2(a2.z, a2.w);
    w1.z = pk2(a3.x, a3.y); w1.w = pk2(a3.z, a3.w);
    *(uint4*)(HsA + srow * 72 + sc0) = w0;
    *(uint4*)(HsA + srow * 72 + sc0 + 8) = w1;
  }
  // prefetch tiles 1 (pa) and 2 (pb)
  a0 = *(const float4*)(srcB + 64);
  a1 = *(const float4*)(srcB + 68);
  a2 = *(const float4*)(srcB + 72);
  a3 = *(const float4*)(srcB + 76);
  float4 b0 = *(const float4*)(srcB + 128);
  float4 b1 = *(const float4*)(srcB + 132);
  float4 b2 = *(const float4*)(srcB + 136);
  float4 b3 = *(const float4*)(srcB + 140);
  for (int kc = 0; kc < 12; kc++) {
    __syncthreads();     // tile kc visible in cur
    short* cur = (kc & 1) ? HsB : HsA;
    short* nxt = (kc & 1) ? HsA : HsB;
    if (kc < 11) {       // store tile kc+1 (held in pa)
      uint4 w0, w1;
      w0.x = pk2(a0.x, a0.y); w0.y = pk2(a0.z, a0.w);
      w0.z = pk2(a1.x, a1.y); w0.w = pk2(a1.z, a1.w);
      w1.x = pk2(a2.x, a2.y); w1.y = pk2(a2.z, a2.w);
      w1.z = pk2(a3.x, a3.y); w1.w = pk2(a3.z, a3.w);
      *(uint4*)(nxt + srow * 72 + sc0) = w0;
      *(uint4*)(nxt + srow * 72 + sc0 + 8) = w1;
    }
    if (kc < 10) {       // shift pb->pa, prefetch tile kc+3
      a0 = b0; a1 = b1; a2 = b2; a3 = b3;
      if (kc < 9) {
        const float* s2 = srcB + (kc + 3) * 64;
        b0 = *(const float4*)(s2);
        b1 = *(const float4*)(s2 + 4);
        b2 = *(const float4*)(s2 + 8);
        b3 = *(const float4*)(s2 + 12);
      }
    }
    #pragma unroll
    for (int ks = 0; ks < 2; ks++) {
      bf16x8 afrag = *(const bf16x8*)(cur + (wv * 16 + fm) * 72 + ks * 32 + fg * 8);
      #pragma unroll
      for (int ct = 0; ct < 8; ct++) {
        bf16x8 bfrag = *(const bf16x8*)(cur + (ct * 16 + fm) * 72 + ks * 32 + fg * 8);
        acc[ct] = __builtin_amdgcn_mfma_f32_16x16x32_bf16(afrag, bfrag, acc[ct], 0, 0, 0);
      }
    }
  }
  __syncthreads();       // all MFMA reads done; Hs dead -> Gm
  #pragma unroll
  for (int ct = 0; ct < 8; ct++) {
    int gc = ct * 16 + fm;
    #pragma unroll
    for (int q2 = 0; q2 < 4; q2++) {
      int gr = wv * 16 + fg * 4 + q2;
      Gm[gr * 130 + gc] = __float2half(acc[ct][q2]);
    }
  }
  if ((fm >> 2) == fg) diag[wv * 16 + fm] = acc[wv][fm & 3];  // f32 diag
  for (int e = t; e < 48 * 116; e += 512) Kr[e] = BIGF;
  __syncthreads();

  // ---- Phase C: compact Ce, shifts, K transform, KT ----
  for (int i = t >> 7; i < n0; i += 4) {
    int ra = ia[i];
    float di = diag[ra];
    for (int j = t & 127; j < n1; j += 128) {
      int cb = ib[j];
      float g = __half2float(Gm[ra * 130 + cb]);
      float d2 = fmaxf(di + diag[cb] - 2.0f * g, 1e-6f);
      Kr[i * 116 + j] = sqrtf(d2) * INV_EPS;
    }
  }
  __syncthreads();
  if (t < 192) {  // r_i = min_j Ce
    int r = t >> 2, c = t & 3;
    const float* row = Kr + r * 116 + c * 28;
    float mn = BIGF;
    #pragma unroll
    for (int g = 0; g < 7; g++) {
      float4 x = *(const float4*)(row + g * 4);
      mn = fminf(mn, fminf(fminf(x.x, x.y), fminf(x.z, x.w)));
    }
    mn = fminf(mn, __shfl_xor(mn, 1));
    mn = fminf(mn, __shfl_xor(mn, 2));
    if (c == 0) rv[r] = mn;
  }
  __syncthreads();
  if (t < 448) {  // c_j = min_{i<n0} (Ce - r_i)
    int cl = t >> 2, rr = t & 3;
    float mn = BIGF;
    #pragma unroll
    for (int g = 0; g < 12; g++) {
      int i = rr * 12 + g;
      float v = (i < n0) ? (Kr[i * 116 + cl] - rv[i]) : BIGF;
      mn = fminf(mn, v);
    }
    mn = fminf(mn, __shfl_xor(mn, 1));
    mn = fminf(mn, __shfl_xor(mn, 2));
    if (rr == 0) cv[cl] = mn;
  }
  __syncthreads();
  for (int i = t >> 7; i < 48; i += 4) {  // K = exp(min(r+c-Ce,0)) in place
    float ri = rv[i];
    for (int j = t & 127; j < 112; j += 128) {
      float ce = Kr[i * 116 + j];
      Kr[i * 116 + j] = __expf(fminf(ri + cv[j] - ce, 0.f));
    }
  }
  __syncthreads();       // Gm dead -> KT
  for (int i = t >> 7; i < 48; i += 4) {
    int j = t & 127;
    if (j < 112) KT[j * 52 + i] = Kr[i * 116 + j];
  }
  __syncthreads();

  // ---- store compact problem to global ws ----
  float* Kg = kdat + (size_t)b * KSTRIDE;
  for (int e = t; e < KRS; e += 512) Kg[e] = Kr[e];
  for (int e = t; e < KTS; e += 512) Kg[KRS + e] = KT[e];
  float* vec = Kg + VECOFF;
  if (t < 48) vec[t] = rv[t];
  if (t >= 64 && t < 176) vec[48 + (t - 64)] = cv[t - 64];
  if (t == 0) {
    vec[160] = 1.0f / (float)n0;
    vec[161] = 1.0f / (float)n1;
    vec[162] = (float)n0;
    vec[163] = (float)n1;
  }
}

__global__ __launch_bounds__(64, 1)
void k_sink(const float* __restrict__ kdat, float* __restrict__ dcross)
{
  const int b = blockIdx.x, l = threadIdx.x;
  __shared__ __align__(16) float uv[48];
  __shared__ __align__(16) float vv[112];

  const float* Kg  = kdat + (size_t)b * KSTRIDE;
  const float* KTg = Kg + KRS;
  const float* vec = Kg + VECOFF;

  const float rl  = vec[(l < 48) ? l : 47];
  const float cv1 = vec[48 + l];
  const float cv2 = (l < 48) ? vec[48 + 64 + l] : 0.f;
  const float inv_n0 = vec[160], inv_n1 = vec[161];
  const int n0 = (int)vec[162], n1 = (int)vec[163];

  const int r48 = (l < 48) ? l : 47;
  const int j2ok = (l < 48);
  const int c2 = j2ok ? (l + 64) : l;
  const float a_l = (l < n0) ? inv_n0 : 0.f;
  const float b1w = (l < n1) ? inv_n1 : 0.f;
  const float b2w = (j2ok && c2 < n1) ? inv_n1 : 0.f;

  // K row + two KT rows into registers
  float4 KR[28], KA[12], KB[12];
  #pragma unroll
  for (int g = 0; g < 28; g++) KR[g] = *(const float4*)(Kg + r48 * 116 + 4 * g);
  #pragma unroll
  for (int g = 0; g < 12; g++) {
    KA[g] = *(const float4*)(KTg + l * 52 + 4 * g);
    KB[g] = *(const float4*)(KTg + c2 * 52 + 4 * g);
  }

  // init v
  vv[l] = (l < n1) ? inv_n1 * __expf(-cv1) : 0.f;
  if (j2ok) vv[l + 64] = (l + 64 < n1) ? inv_n1 * __expf(-cv2) : 0.f;
  __asm__ volatile("s_waitcnt lgkmcnt(0)" ::: "memory");

  float Sl = 1.f, Tc1 = 1.f, Tc2 = 1.f;
  for (int it = 0; it < 30; it++) {
    // u-step: lane l = row l
    float s0 = 0.f, s1 = 0.f, s2 = 0.f, s3 = 0.f;
    #pragma unroll
    for (int g = 0; g < 28; g++) {
      float4 v4 = *(const float4*)(vv + 4 * g);   // LDS broadcast
      s0 += KR[g].x * v4.x; s1 += KR[g].y * v4.y;
      s2 += KR[g].z * v4.z; s3 += KR[g].w * v4.w;
    }
    float S = (s0 + s1) + (s2 + s3);
    Sl = S;
    if (l < 48) uv[l] = a_l * __builtin_amdgcn_rcpf(S);
    __asm__ volatile("s_waitcnt lgkmcnt(0)" ::: "memory");
    // v-step: lane l = cols l, l+64
    float p0 = 0.f, p1 = 0.f, q0 = 0.f, q1 = 0.f;
    #pragma unroll
    for (int g = 0; g < 12; g++) {
      float4 u4 = *(const float4*)(uv + 4 * g);   // LDS broadcast
      p0 += KA[g].x * u4.x + KA[g].z * u4.z;
      p1 += KA[g].y * u4.y + KA[g].w * u4.w;
      q0 += KB[g].x * u4.x + KB[g].z * u4.z;
      q1 += KB[g].y * u4.y + KB[g].w * u4.w;
    }
    float T1 = p0 + p1, T2 = q0 + q1;
    Tc1 = T1; Tc2 = T2;
    vv[l] = b1w * __builtin_amdgcn_rcpf(T1);
    if (j2ok) vv[l + 64] = b2w * __builtin_amdgcn_rcpf(T2);
    __asm__ volatile("s_waitcnt lgkmcnt(0)" ::: "memory");
  }
  // dual value, 64-lane butterfly
  float val = (l < n0) ? inv_n0 * (rl - __logf(Sl)) : 0.f;
  if (l < n1) val += inv_n1 * (cv1 - __logf(Tc1));
  if (j2ok && c2 < n1) val += inv_n1 * (cv2 - __logf(Tc2));
  #pragma unroll
  for (int d = 1; d < 64; d <<= 1) val += __shfl_xor(val, d);
  if (l == 0) dcross[b] = EPS * val;
}

// ---- rep builder: cls + masked mean-diff, output f16 [64][1536] ----
__global__ __launch_bounds__(512)
void k_rep(const float* __restrict__ H, const int* __restrict__ ttid,
           const int* __restrict__ amask,
           float* __restrict__ cnt, _Float16* __restrict__ rep_h)
{
  const int b = blockIdx.x, t = threadIdx.x;
  __shared__ float part0[4][768];
  __shared__ float part1[4][768];
  __shared__ float afl[128], bfl[128], red[2];

  if (t < 128) {
    int a_ = amask[b*128 + t], tt_ = ttid[b*128 + t];
    afl[t] = (a_ == 1 && tt_ == 0) ? 1.0f : 0.0f;
    bfl[t] = (a_ == 1 && tt_ == 1) ? 1.0f : 0.0f;
  }
  __syncthreads();
  if (t < 64) {
    float s = afl[t] + afl[t + 64];
    #pragma unroll
    for (int d = 32; d > 0; d >>= 1) s += __shfl_down(s, d);
    if (t == 0) red[0] = s;
  } else if (t < 128) {
    int l = t - 64;
    float s = bfl[l] + bfl[l + 64];
    #pragma unroll
    for (int d = 32; d > 0; d >>= 1) s += __shfl_down(s, d);
    if (l == 0) red[1] = s;
  }
  __syncthreads();
  const float n0 = fmaxf(red[0], 1.0f), n1 = fmaxf(red[1], 1.0f);
  if (t == 0) { cnt[b*2] = n0; cnt[b*2 + 1] = n1; }

  // 4-way token-split partial sums: thread (g,r) sums 32 tokens x 6 dims
  const int g = t >> 7, r = t & 127;
  const float* Hb = H + (size_t)b * (128 * 768);
  float s0[6] = {0,0,0,0,0,0}, s1[6] = {0,0,0,0,0,0};
  #pragma unroll 4
  for (int ii = 0; ii < 32; ii++) {
    int i = g * 32 + ii;
    float a = afl[i], w = bfl[i];
    #pragma unroll
    for (int j = 0; j < 6; j++) {
      float h = Hb[i * 768 + r + 128 * j];
      s0[j] = fmaf(a, h, s0[j]);
      s1[j] = fmaf(w, h, s1[j]);
    }
  }
  #pragma unroll
  for (int j = 0; j < 6; j++) {
    part0[g][r + 128 * j] = s0[j];
    part1[g][r + 128 * j] = s1[j];
  }
  __syncthreads();
  const float in0 = 1.0f / n0, in1 = 1.0f / n1;
  for (int d = t; d < 768; d += 512) {
    float m0 = part0[0][d] + part0[1][d] + part0[2][d] + part0[3][d];
    float m1 = part1[0][d] + part1[1][d] + part1[2][d] + part1[3][d];
    rep_h[(size_t)b * 1536 + d]       = (_Float16)Hb[d];          // cls
    rep_h[(size_t)b * 1536 + 768 + d] = (_Float16)(m0 * in0 - m1 * in1);
  }
}

// ---- MLP GEMM: raw[64][320] = rep_h @ [Wc;Ws]^T, f16 MFMA ----
#define WLD_STRIDE 1544
__global__ __launch_bounds__(512)
void k_gemm(const float* __restrict__ Wc, const float* __restrict__ Ws,
            const _Float16* __restrict__ rep_h, float* __restrict__ rawout)
{
  __shared__ _Float16 Wlds[16 * WLD_STRIDE];   // 49408 B
  __shared__ float redb[4][64][4];             // 4096 B
  const int j = blockIdx.x;                    // 20 blocks: outputs [16j,16j+16)
  const int t = threadIdx.x;
  const int obase = j * 16;
  const float* Wsrc = (obase < 256) ? (Wc + (size_t)obase * 1536)
                                    : (Ws + (size_t)(obase - 256) * 1536);
  {   // stage + convert 16x1536 f32 -> f16 LDS
    const int r = t >> 5, c = t & 31;
    const float* src = Wsrc + (size_t)r * 1536;
    #pragma unroll
    for (int q = 0; q < 12; q++) {
      float4 w4 = *(const float4*)(src + c * 4 + 128 * q);
      f16x4 h4 = { (_Float16)w4.x, (_Float16)w4.y, (_Float16)w4.z, (_Float16)w4.w };
      *(f16x4*)(Wlds + r * WLD_STRIDE + c * 4 + 128 * q) = h4;
    }
  }
  __syncthreads();

  const int wave = t >> 6, lane = t & 63;
  const int bt = wave & 3;         // batch-tile (16 batches)
  const int kh = wave >> 1 >> 1;   // K-half (wave>>2)
  const int fm = lane & 15, fg = lane >> 4;
  const _Float16* arow = Wlds + fm * WLD_STRIDE + fg * 8;
  const _Float16* brow = rep_h + (size_t)(bt * 16 + fm) * 1536 + fg * 8;
  f32x4 acc = {0.f, 0.f, 0.f, 0.f};
  #pragma unroll 4
  for (int s = 0; s < 24; s++) {
    int k0 = kh * 768 + s * 32;
    f16x8 af = *(const f16x8*)(arow + k0);
    f16x8 bf = *(const f16x8*)(brow + k0);
    acc = __builtin_amdgcn_mfma_f32_16x16x32_f16(af, bf, acc, 0, 0, 0);
  }
  if (wave >= 4) {
    #pragma unroll
    for (int q = 0; q < 4; q++) redb[bt][lane][q] = acc[q];
  }
  __syncthreads();
  if (wave < 4) {
    const int bb = bt * 16 + fm;       // batch (D col = lane&15)
    #pragma unroll
    for (int q = 0; q < 4; q++) {
      int o = obase + fg * 4 + q;      // output (D row = (lane>>4)*4+reg)
      rawout[(size_t)bb * 320 + o] = acc[q] + redb[bt][lane][q];
    }
  }
}

__global__ __launch_bounds__(128)
void k_final(const float* __restrict__ rawout, const float* __restrict__ dcross,
             const float* __restrict__ cnt,
             const float* __restrict__ bc, const float* __restrict__ bs,
             const float* __restrict__ gate,
             const float* __restrict__ lnw, const float* __restrict__ lnb,
             const float* __restrict__ Wcls, const float* __restrict__ bcls,
             float* __restrict__ out)
{
  const int b = blockIdx.x, t = threadIdx.x;
  __shared__ float feat[321];
  __shared__ float sred[4];
  const float g = 1.0f / (1.0f + __expf(-gate[0]));
  for (int i = t; i < 320; i += 128) {
    float bias = (i < 256) ? bc[i] : bs[i - 256];
    float fac  = (i < 256) ? (1.0f - g) : g;
    feat[i] = (rawout[b * 320 + i] + bias) * fac;
  }
  if (t == 0) {
    float n0 = cnt[b*2], n1 = cnt[b*2 + 1];
    float dsa = EPS * __logf(n0) + 0.001f;   // collapsed self-Sinkhorn
    float dsb = EPS * __logf(n1) + 0.001f;
    feat[320] = dcross[b] - 0.5f * (dsa + dsb);
  }
  __syncthreads();
  float s = 0.f;
  for (int i = t; i < 321; i += 128) s += feat[i];
  #pragma unroll
  for (int d = 32; d > 0; d >>= 1) s += __shfl_down(s, d);
  if ((t & 63) == 0) sred[t >> 6] = s;
  __syncthreads();
  const float mu = (sred[0] + sred[1]) * (1.0f / 321.0f);
  __syncthreads();
  float v = 0.f;
  for (int i = t; i < 321; i += 128) { float d2 = feat[i] - mu; v += d2 * d2; }
  #pragma unroll
  for (int d = 32; d > 0; d >>= 1) v += __shfl_down(v, d);
  if ((t & 63) == 0) sred[t >> 6] = v;
  __syncthreads();
  const float rstd = rsqrtf((sred[0] + sred[1]) * (1.0f / 321.0f) + 1e-5f);
  __syncthreads();
  float p0 = 0.f, p1 = 0.f;
  for (int i = t; i < 321; i += 128) {
    float h = (feat[i] - mu) * rstd * lnw[i] + lnb[i];
    p0 += h * Wcls[i];
    p1 += h * Wcls[321 + i];
  }
  #pragma unroll
  for (int d = 32; d > 0; d >>= 1) { p0 += __shfl_down(p0, d); p1 += __shfl_down(p1, d); }
  if ((t & 63) == 0) { sred[t >> 6] = p0; sred[2 + (t >> 6)] = p1; }
  __syncthreads();
  if (t == 0) {
    out[b * 2]     = sred[0] + sred[1] + bcls[0];
    out[b * 2 + 1] = sred[2] + sred[3] + bcls[1];
  }
}

extern "C" void kernel_launch(void* const* d_in, const int* in_sizes, int n_in,
                              void* d_out, int out_size, void* d_ws, size_t ws_size,
                              hipStream_t stream)
{
  (void)in_sizes; (void)n_in; (void)out_size; (void)ws_size;
  const float* H    = (const float*)d_in[0];
  const int*   tt   = (const int*)d_in[1];
  const int*   am   = (const int*)d_in[2];
  const float* Wc   = (const float*)d_in[3];
  const float* bc   = (const float*)d_in[4];
  const float* Ws   = (const float*)d_in[5];
  const float* bs   = (const float*)d_in[6];
  const float* gate = (const float*)d_in[7];
  const float* lnw  = (const float*)d_in[8];
  const float* lnb  = (const float*)d_in[9];
  const float* Wcls = (const float*)d_in[10];
  const float* bcls = (const float*)d_in[11];
  float* out = (float*)d_out;

  float* dcross = (float*)d_ws;            // 64 floats
  float* cntv   = dcross + 64;             // 128 floats
  float* rawout = cntv + 128;              // 64*320 floats
  float* kdat   = rawout + 64 * 320;       // 64*KSTRIDE floats (~2.97 MB)
  // rep_h ALIASES kdat: k_rep runs after k_sink (stream-ordered), kdat dead.
  _Float16* rep_h = (_Float16*)kdat;       // 64*1536 f16 = 196 KB

  k_gram<<<dim3(64), dim3(512), 0, stream>>>(H, tt, am, kdat);
  k_sink<<<dim3(64), dim3(64), 0, stream>>>(kdat, dcross);
  k_rep<<<dim3(64), dim3(512), 0, stream>>>(H, tt, am, cntv, rep_h);
  k_gemm<<<dim3(20), dim3(512), 0, stream>>>(Wc, Ws, rep_h, rawout);
  k_final<<<dim3(64), dim3(128), 0, stream>>>(rawout, dcross, cntv, bc, bs,
                                              gate, lnw, lnb, Wcls, bcls, out);
}

// Round 7
// 148.069 us; speedup vs baseline: 1.3042x; 1.0736x over previous
//
#include <hip/hip_runtime.h>
#include <hip/hip_fp16.h>
#include <math.h>

#define EPS 0.05f
#define INV_EPS 20.0f
#define BIGF 1e30f

typedef short bf16x8 __attribute__((ext_vector_type(8)));
typedef float f32x4 __attribute__((ext_vector_type(4)));
typedef _Float16 f16x8 __attribute__((ext_vector_type(8)));
typedef _Float16 f16x4 __attribute__((ext_vector_type(4)));

__device__ __forceinline__ unsigned f2bf(float x) {
  unsigned u = __float_as_uint(x);
  return (u + 0x7fffu + ((u >> 16) & 1u)) >> 16;  // RNE f32->bf16
}
__device__ __forceinline__ unsigned pk2(float a, float b) {
  return (f2bf(a) & 0xffffu) | (f2bf(b) << 16);
}

// ---- k_front Sinkhorn-branch LDS arena (bytes); aliasing by lifetime ----
#define S_HSA  0        // short[128][72] = 18432
#define S_HSB  18432    //              -> 36864
#define S_GM   0        // half[128][130] = 33280 (alias, Hs dead)
#define S_KT   0        // float[112][52] = 23296 (alias, Gm dead)
#define S_KR   36864    // float[48][116] = 22272 -> 59136
#define S_DIAG 59136    // f32[128] -> 59648
#define S_IA   59648    // int[48]  -> 59840
#define S_IB   59840    // int[112] -> 60288
#define S_RV   60288    // f32[48]  -> 60480
#define S_CV   60480    // f32[112] -> 60928
#define S_UV   60928    // f32[48]  -> 61120
#define S_VV   61120    // f32[112] -> 61568
#define S_CNT  61568    // int[4]   -> 61584
#define SMEM_SZ 61632
// rep-branch offsets (same smem array): part0 0..12288, part1 ..24576,
// afl 24576..25088, bfl ..25600, red ..25608  (all < SMEM_SZ)

__global__ __launch_bounds__(512)
void k_front(const float* __restrict__ H, const int* __restrict__ ttid,
             const int* __restrict__ amask,
             float* __restrict__ dcross, float* __restrict__ cnt,
             _Float16* __restrict__ rep_h)
{
  __shared__ __align__(16) char smem[SMEM_SZ];
  const int t = threadIdx.x;
  const int bid = blockIdx.x;

  if (bid < 64) {
    // ============ full Sinkhorn in one kernel (no global round-trip) =======
    const int b = bid;
    short*  HsA  = (short*)(smem + S_HSA);
    short*  HsB  = (short*)(smem + S_HSB);
    __half* Gm   = (__half*)(smem + S_GM);
    float*  KT   = (float*)(smem + S_KT);
    float*  Kr   = (float*)(smem + S_KR);
    float*  diag = (float*)(smem + S_DIAG);
    int*    ia   = (int*)(smem + S_IA);
    int*    ib   = (int*)(smem + S_IB);
    float*  rv   = (float*)(smem + S_RV);
    float*  cv   = (float*)(smem + S_CV);
    float*  uv   = (float*)(smem + S_UV);
    float*  vv   = (float*)(smem + S_VV);
    int*    cnts = (int*)(smem + S_CNT);

    const int lane = t & 63;
    const int w = t >> 6;

    // ---- Phase A: compact index lists via ballot prefix-sum ----
    int flagA = 0, flagB = 0;
    unsigned long long mA = 0, mB = 0;
    if (t < 128) {
      int a_ = amask[b*128 + t], tt_ = ttid[b*128 + t];
      flagA = (a_ == 1 && tt_ == 0);
      flagB = (a_ == 1 && tt_ == 1);
      mA = __ballot(flagA);
      mB = __ballot(flagB);
      if (lane == 0) { cnts[w] = __popcll(mA); cnts[2 + w] = __popcll(mB); }
    }
    __syncthreads();
    const int n0 = cnts[0] + cnts[1];
    const int n1 = cnts[2] + cnts[3];
    if (t < 128) {
      int offA = (w == 1) ? cnts[0] : 0;
      int offB = (w == 1) ? cnts[2] : 0;
      unsigned long long below = (1ull << lane) - 1ull;
      if (flagA) ia[offA + __popcll(mA & below)] = t;
      if (flagB) ib[offB + __popcll(mB & below)] = t;
    }

    // ---- Phase B: Gram via bf16 MFMA, depth-2 prefetched staging ----
    const int wv = t >> 6;
    const int fm = lane & 15, fg = lane >> 4;
    f32x4 acc[8];
    #pragma unroll
    for (int ct = 0; ct < 8; ct++) {
      acc[ct][0] = 0.f; acc[ct][1] = 0.f; acc[ct][2] = 0.f; acc[ct][3] = 0.f;
    }
    const float* Hb = H + (size_t)b * (128 * 768);
    const int srow = t >> 2, sc0 = (t & 3) * 16;
    const float* srcB = Hb + srow * 768 + sc0;
    float4 a0 = *(const float4*)(srcB);
    float4 a1 = *(const float4*)(srcB + 4);
    float4 a2 = *(const float4*)(srcB + 8);
    float4 a3 = *(const float4*)(srcB + 12);
    {   // store tile 0 -> HsA
      uint4 w0, w1;
      w0.x = pk2(a0.x, a0.y); w0.y = pk2(a0.z, a0.w);
      w0.z = pk2(a1.x, a1.y); w0.w = pk2(a1.z, a1.w);
      w1.x = pk2(a2.x, a2.y); w1.y = pk2(a2.z, a2.w);
      w1.z = pk2(a3.x, a3.y); w1.w = pk2(a3.z, a3.w);
      *(uint4*)(HsA + srow * 72 + sc0) = w0;
      *(uint4*)(HsA + srow * 72 + sc0 + 8) = w1;
    }
    // prefetch tiles 1 (a-regs) and 2 (b-regs)
    a0 = *(const float4*)(srcB + 64);
    a1 = *(const float4*)(srcB + 68);
    a2 = *(const float4*)(srcB + 72);
    a3 = *(const float4*)(srcB + 76);
    float4 b0 = *(const float4*)(srcB + 128);
    float4 b1 = *(const float4*)(srcB + 132);
    float4 b2 = *(const float4*)(srcB + 136);
    float4 b3 = *(const float4*)(srcB + 140);
    for (int kc = 0; kc < 12; kc++) {
      __syncthreads();     // tile kc visible in cur
      short* cur = (kc & 1) ? HsB : HsA;
      short* nxt = (kc & 1) ? HsA : HsB;
      if (kc < 11) {       // store tile kc+1
        uint4 w0, w1;
        w0.x = pk2(a0.x, a0.y); w0.y = pk2(a0.z, a0.w);
        w0.z = pk2(a1.x, a1.y); w0.w = pk2(a1.z, a1.w);
        w1.x = pk2(a2.x, a2.y); w1.y = pk2(a2.z, a2.w);
        w1.z = pk2(a3.x, a3.y); w1.w = pk2(a3.z, a3.w);
        *(uint4*)(nxt + srow * 72 + sc0) = w0;
        *(uint4*)(nxt + srow * 72 + sc0 + 8) = w1;
      }
      if (kc < 10) {       // shift, prefetch tile kc+3
        a0 = b0; a1 = b1; a2 = b2; a3 = b3;
        if (kc < 9) {
          const float* s2 = srcB + (kc + 3) * 64;
          b0 = *(const float4*)(s2);
          b1 = *(const float4*)(s2 + 4);
          b2 = *(const float4*)(s2 + 8);
          b3 = *(const float4*)(s2 + 12);
        }
      }
      #pragma unroll
      for (int ks = 0; ks < 2; ks++) {
        bf16x8 afrag = *(const bf16x8*)(cur + (wv * 16 + fm) * 72 + ks * 32 + fg * 8);
        #pragma unroll
        for (int ct = 0; ct < 8; ct++) {
          bf16x8 bfrag = *(const bf16x8*)(cur + (ct * 16 + fm) * 72 + ks * 32 + fg * 8);
          acc[ct] = __builtin_amdgcn_mfma_f32_16x16x32_bf16(afrag, bfrag, acc[ct], 0, 0, 0);
        }
      }
    }
    __syncthreads();       // Hs dead -> Gm
    #pragma unroll
    for (int ct = 0; ct < 8; ct++) {
      int gc = ct * 16 + fm;
      #pragma unroll
      for (int q2 = 0; q2 < 4; q2++) {
        int gr = wv * 16 + fg * 4 + q2;
        Gm[gr * 130 + gc] = __float2half(acc[ct][q2]);
      }
    }
    if ((fm >> 2) == fg) diag[wv * 16 + fm] = acc[wv][fm & 3];  // f32 diag
    for (int e = t; e < 48 * 116; e += 512) Kr[e] = BIGF;
    __syncthreads();

    // ---- Phase C: compact Ce, shifts, K transform, KT ----
    for (int i = t >> 7; i < n0; i += 4) {
      int ra = ia[i];
      float di = diag[ra];
      for (int j = t & 127; j < n1; j += 128) {
        int cb = ib[j];
        float g = __half2float(Gm[ra * 130 + cb]);
        float d2 = fmaxf(di + diag[cb] - 2.0f * g, 1e-6f);
        Kr[i * 116 + j] = sqrtf(d2) * INV_EPS;
      }
    }
    __syncthreads();
    if (t < 192) {  // r_i = min_j Ce
      int r = t >> 2, c = t & 3;
      const float* row = Kr + r * 116 + c * 28;
      float mn = BIGF;
      #pragma unroll
      for (int g = 0; g < 7; g++) {
        float4 x = *(const float4*)(row + g * 4);
        mn = fminf(mn, fminf(fminf(x.x, x.y), fminf(x.z, x.w)));
      }
      mn = fminf(mn, __shfl_xor(mn, 1));
      mn = fminf(mn, __shfl_xor(mn, 2));
      if (c == 0) rv[r] = mn;
    }
    __syncthreads();
    if (t < 448) {  // c_j = min_{i<n0} (Ce - r_i)
      int cl = t >> 2, rr = t & 3;
      float mn = BIGF;
      #pragma unroll
      for (int g = 0; g < 12; g++) {
        int i = rr * 12 + g;
        float v = (i < n0) ? (Kr[i * 116 + cl] - rv[i]) : BIGF;
        mn = fminf(mn, v);
      }
      mn = fminf(mn, __shfl_xor(mn, 1));
      mn = fminf(mn, __shfl_xor(mn, 2));
      if (rr == 0) cv[cl] = mn;
    }
    __syncthreads();
    for (int i = t >> 7; i < 48; i += 4) {  // K = exp(min(r+c-Ce,0)) in place
      float ri = rv[i];
      for (int j = t & 127; j < 112; j += 128) {
        float ce = Kr[i * 116 + j];
        Kr[i * 116 + j] = __expf(fminf(ri + cv[j] - ce, 0.f));
      }
    }
    __syncthreads();       // Gm dead -> KT
    for (int i = t >> 7; i < 48; i += 4) {
      int j = t & 127;
      if (j < 112) KT[j * 52 + i] = Kr[i * 116 + j];
    }
    __syncthreads();       // LAST barrier; waves 1-7 idle after this

    // ---- Phase D: single wave, register-resident K, zero barriers ----
    if (t < 64) {
      const int l = t;
      const int r48 = (l < 48) ? l : 47;
      const int j2ok = (l < 48);
      const int c2 = j2ok ? (l + 64) : l;
      const float inv_n0 = 1.0f / (float)n0;
      const float inv_n1 = 1.0f / (float)n1;
      const float rl  = rv[r48];
      const float cv1 = cv[l];
      const float cv2 = j2ok ? cv[l + 64] : 0.f;
      const float a_l = (l < n0) ? inv_n0 : 0.f;
      const float b1w = (l < n1) ? inv_n1 : 0.f;
      const float b2w = (j2ok && c2 < n1) ? inv_n1 : 0.f;

      float4 KRr[28], KA[12], KB[12];
      #pragma unroll
      for (int g = 0; g < 28; g++) KRr[g] = *(const float4*)(Kr + r48 * 116 + 4 * g);
      #pragma unroll
      for (int g = 0; g < 12; g++) {
        KA[g] = *(const float4*)(KT + l * 52 + 4 * g);
        KB[g] = *(const float4*)(KT + c2 * 52 + 4 * g);
      }

      vv[l] = (l < n1) ? inv_n1 * __expf(-cv1) : 0.f;
      if (j2ok) vv[l + 64] = (l + 64 < n1) ? inv_n1 * __expf(-cv2) : 0.f;
      __asm__ volatile("s_waitcnt lgkmcnt(0)" ::: "memory");

      float Sl = 1.f, Tc1 = 1.f, Tc2 = 1.f;
      for (int it = 0; it < 30; it++) {
        float s0 = 0.f, s1 = 0.f, s2 = 0.f, s3 = 0.f;
        #pragma unroll
        for (int g = 0; g < 28; g++) {
          float4 v4 = *(const float4*)(vv + 4 * g);   // LDS broadcast
          s0 += KRr[g].x * v4.x; s1 += KRr[g].y * v4.y;
          s2 += KRr[g].z * v4.z; s3 += KRr[g].w * v4.w;
        }
        float S = (s0 + s1) + (s2 + s3);
        Sl = S;
        if (l < 48) uv[l] = a_l * __builtin_amdgcn_rcpf(S);
        __asm__ volatile("s_waitcnt lgkmcnt(0)" ::: "memory");
        float p0 = 0.f, p1 = 0.f, q0 = 0.f, q1 = 0.f;
        #pragma unroll
        for (int g = 0; g < 12; g++) {
          float4 u4 = *(const float4*)(uv + 4 * g);   // LDS broadcast
          p0 += KA[g].x * u4.x + KA[g].z * u4.z;
          p1 += KA[g].y * u4.y + KA[g].w * u4.w;
          q0 += KB[g].x * u4.x + KB[g].z * u4.z;
          q1 += KB[g].y * u4.y + KB[g].w * u4.w;
        }
        float T1 = p0 + p1, T2 = q0 + q1;
        Tc1 = T1; Tc2 = T2;
        vv[l] = b1w * __builtin_amdgcn_rcpf(T1);
        if (j2ok) vv[c2] = b2w * __builtin_amdgcn_rcpf(T2);
        __asm__ volatile("s_waitcnt lgkmcnt(0)" ::: "memory");
      }
      float val = (l < n0) ? inv_n0 * (rl - __logf(Sl)) : 0.f;
      if (l < n1) val += inv_n1 * (cv1 - __logf(Tc1));
      if (j2ok && c2 < n1) val += inv_n1 * (cv2 - __logf(Tc2));
      #pragma unroll
      for (int d = 1; d < 64; d <<= 1) val += __shfl_xor(val, d);
      if (l == 0) dcross[b] = EPS * val;
    }
  } else {
    // ============ rep builder (concurrent with Sinkhorn blocks) ============
    const int b = bid - 64;
    float* part0 = (float*)smem;                // [4][768]
    float* part1 = (float*)(smem + 12288);      // [4][768]
    float* afl   = (float*)(smem + 24576);      // [128]
    float* bfl   = (float*)(smem + 25088);      // [128]
    float* red   = (float*)(smem + 25600);      // [2]

    if (t < 128) {
      int a_ = amask[b*128 + t], tt_ = ttid[b*128 + t];
      afl[t] = (a_ == 1 && tt_ == 0) ? 1.0f : 0.0f;
      bfl[t] = (a_ == 1 && tt_ == 1) ? 1.0f : 0.0f;
    }
    __syncthreads();
    if (t < 64) {
      float s = afl[t] + afl[t + 64];
      #pragma unroll
      for (int d = 32; d > 0; d >>= 1) s += __shfl_down(s, d);
      if (t == 0) red[0] = s;
    } else if (t < 128) {
      int l = t - 64;
      float s = bfl[l] + bfl[l + 64];
      #pragma unroll
      for (int d = 32; d > 0; d >>= 1) s += __shfl_down(s, d);
      if (l == 0) red[1] = s;
    }
    __syncthreads();
    const float n0 = fmaxf(red[0], 1.0f), n1 = fmaxf(red[1], 1.0f);
    if (t == 0) { cnt[b*2] = n0; cnt[b*2 + 1] = n1; }

    // 4-way token-split partial sums: thread (g,r) sums 32 tokens x 6 dims
    const int g = t >> 7, r = t & 127;
    const float* Hb = H + (size_t)b * (128 * 768);
    float s0[6] = {0,0,0,0,0,0}, s1[6] = {0,0,0,0,0,0};
    #pragma unroll 4
    for (int ii = 0; ii < 32; ii++) {
      int i = g * 32 + ii;
      float a = afl[i], wgt = bfl[i];
      #pragma unroll
      for (int j = 0; j < 6; j++) {
        float h = Hb[i * 768 + r + 128 * j];
        s0[j] = fmaf(a, h, s0[j]);
        s1[j] = fmaf(wgt, h, s1[j]);
      }
    }
    #pragma unroll
    for (int j = 0; j < 6; j++) {
      part0[g * 768 + r + 128 * j] = s0[j];
      part1[g * 768 + r + 128 * j] = s1[j];
    }
    __syncthreads();
    const float in0 = 1.0f / n0, in1 = 1.0f / n1;
    for (int d = t; d < 768; d += 512) {
      float m0 = part0[d] + part0[768 + d] + part0[1536 + d] + part0[2304 + d];
      float m1 = part1[d] + part1[768 + d] + part1[1536 + d] + part1[2304 + d];
      rep_h[(size_t)b * 1536 + d]       = (_Float16)Hb[d];          // cls
      rep_h[(size_t)b * 1536 + 768 + d] = (_Float16)(m0 * in0 - m1 * in1);
    }
  }
}

// ---- MLP GEMM: raw[64][320] = rep_h @ [Wc;Ws]^T, f16 MFMA ----
#define WLD_STRIDE 1544
__global__ __launch_bounds__(512)
void k_gemm(const float* __restrict__ Wc, const float* __restrict__ Ws,
            const _Float16* __restrict__ rep_h, float* __restrict__ rawout)
{
  __shared__ _Float16 Wlds[16 * WLD_STRIDE];   // 49408 B
  __shared__ float redb[4][64][4];             // 4096 B
  const int j = blockIdx.x;                    // 20 blocks: outputs [16j,16j+16)
  const int t = threadIdx.x;
  const int obase = j * 16;
  const float* Wsrc = (obase < 256) ? (Wc + (size_t)obase * 1536)
                                    : (Ws + (size_t)(obase - 256) * 1536);
  {   // stage + convert 16x1536 f32 -> f16 LDS
    const int r = t >> 5, c = t & 31;
    const float* src = Wsrc + (size_t)r * 1536;
    #pragma unroll
    for (int q = 0; q < 12; q++) {
      float4 w4 = *(const float4*)(src + c * 4 + 128 * q);
      f16x4 h4 = { (_Float16)w4.x, (_Float16)w4.y, (_Float16)w4.z, (_Float16)w4.w };
      *(f16x4*)(Wlds + r * WLD_STRIDE + c * 4 + 128 * q) = h4;
    }
  }
  __syncthreads();

  const int wave = t >> 6, lane = t & 63;
  const int bt = wave & 3;         // batch-tile (16 batches)
  const int kh = wave >> 2;        // K-half
  const int fm = lane & 15, fg = lane >> 4;
  const _Float16* arow = Wlds + fm * WLD_STRIDE + fg * 8;
  const _Float16* brow = rep_h + (size_t)(bt * 16 + fm) * 1536 + fg * 8;
  f32x4 acc = {0.f, 0.f, 0.f, 0.f};
  #pragma unroll 4
  for (int s = 0; s < 24; s++) {
    int k0 = kh * 768 + s * 32;
    f16x8 af = *(const f16x8*)(arow + k0);
    f16x8 bf = *(const f16x8*)(brow + k0);
    acc = __builtin_amdgcn_mfma_f32_16x16x32_f16(af, bf, acc, 0, 0, 0);
  }
  if (wave >= 4) {
    #pragma unroll
    for (int q = 0; q < 4; q++) redb[bt][lane][q] = acc[q];
  }
  __syncthreads();
  if (wave < 4) {
    const int bb = bt * 16 + fm;       // batch (D col = lane&15)
    #pragma unroll
    for (int q = 0; q < 4; q++) {
      int o = obase + fg * 4 + q;      // output (D row = (lane>>4)*4+reg)
      rawout[(size_t)bb * 320 + o] = acc[q] + redb[bt][lane][q];
    }
  }
}

__global__ __launch_bounds__(128)
void k_final(const float* __restrict__ rawout, const float* __restrict__ dcross,
             const float* __restrict__ cnt,
             const float* __restrict__ bc, const float* __restrict__ bs,
             const float* __restrict__ gate,
             const float* __restrict__ lnw, const float* __restrict__ lnb,
             const float* __restrict__ Wcls, const float* __restrict__ bcls,
             float* __restrict__ out)
{
  const int b = blockIdx.x, t = threadIdx.x;
  __shared__ float feat[321];
  __shared__ float sred[4];
  const float g = 1.0f / (1.0f + __expf(-gate[0]));
  for (int i = t; i < 320; i += 128) {
    float bias = (i < 256) ? bc[i] : bs[i - 256];
    float fac  = (i < 256) ? (1.0f - g) : g;
    feat[i] = (rawout[b * 320 + i] + bias) * fac;
  }
  if (t == 0) {
    float n0 = cnt[b*2], n1 = cnt[b*2 + 1];
    float dsa = EPS * __logf(n0) + 0.001f;   // collapsed self-Sinkhorn
    float dsb = EPS * __logf(n1) + 0.001f;
    feat[320] = dcross[b] - 0.5f * (dsa + dsb);
  }
  __syncthreads();
  float s = 0.f;
  for (int i = t; i < 321; i += 128) s += feat[i];
  #pragma unroll
  for (int d = 32; d > 0; d >>= 1) s += __shfl_down(s, d);
  if ((t & 63) == 0) sred[t >> 6] = s;
  __syncthreads();
  const float mu = (sred[0] + sred[1]) * (1.0f / 321.0f);
  __syncthreads();
  float v = 0.f;
  for (int i = t; i < 321; i += 128) { float d2 = feat[i] - mu; v += d2 * d2; }
  #pragma unroll
  for (int d = 32; d > 0; d >>= 1) v += __shfl_down(v, d);
  if ((t & 63) == 0) sred[t >> 6] = v;
  __syncthreads();
  const float rstd = rsqrtf((sred[0] + sred[1]) * (1.0f / 321.0f) + 1e-5f);
  __syncthreads();
  float p0 = 0.f, p1 = 0.f;
  for (int i = t; i < 321; i += 128) {
    float h = (feat[i] - mu) * rstd * lnw[i] + lnb[i];
    p0 += h * Wcls[i];
    p1 += h * Wcls[321 + i];
  }
  #pragma unroll
  for (int d = 32; d > 0; d >>= 1) { p0 += __shfl_down(p0, d); p1 += __shfl_down(p1, d); }
  if ((t & 63) == 0) { sred[t >> 6] = p0; sred[2 + (t >> 6)] = p1; }
  __syncthreads();
  if (t == 0) {
    out[b * 2]     = sred[0] + sred[1] + bcls[0];
    out[b * 2 + 1] = sred[2] + sred[3] + bcls[1];
  }
}

extern "C" void kernel_launch(void* const* d_in, const int* in_sizes, int n_in,
                              void* d_out, int out_size, void* d_ws, size_t ws_size,
                              hipStream_t stream)
{
  (void)in_sizes; (void)n_in; (void)out_size; (void)ws_size;
  const float* H    = (const float*)d_in[0];
  const int*   tt   = (const int*)d_in[1];
  const int*   am   = (const int*)d_in[2];
  const float* Wc   = (const float*)d_in[3];
  const float* bc   = (const float*)d_in[4];
  const float* Ws   = (const float*)d_in[5];
  const float* bs   = (const float*)d_in[6];
  const float* gate = (const float*)d_in[7];
  const float* lnw  = (const float*)d_in[8];
  const float* lnb  = (const float*)d_in[9];
  const float* Wcls = (const float*)d_in[10];
  const float* bcls = (const float*)d_in[11];
  float* out = (float*)d_out;

  float* dcross = (float*)d_ws;            // 64 floats
  float* cntv   = dcross + 64;             // 128 floats
  float* rawout = cntv + 128;              // 64*320 floats
  _Float16* rep_h = (_Float16*)(rawout + 64 * 320);  // 64*1536 f16 = 196 KB

  k_front<<<dim3(128), dim3(512), 0, stream>>>(H, tt, am, dcross, cntv, rep_h);
  k_gemm<<<dim3(20), dim3(512), 0, stream>>>(Wc, Ws, rep_h, rawout);
  k_final<<<dim3(64), dim3(128), 0, stream>>>(rawout, dcross, cntv, bc, bs,
                                              gate, lnw, lnb, Wcls, bcls, out);
}